// Round 14
// baseline (1726.789 us; speedup 1.0000x reference)
//
#include <hip/hip_runtime.h>
#include <hip/hip_fp16.h>

#define B_ 256
#define T_ 4096
#define I_ 64
#define H_ 36
#define G_ 144   // 4*H
#define O_ 2
#define TS 32

typedef __fp16 h2 __attribute__((ext_vector_type(2)));

__device__ __forceinline__ float fsigmoid(float x) {
  float e = __builtin_amdgcn_exp2f(x * -1.442695040888963f);
  return __builtin_amdgcn_rcpf(1.0f + e);
}
__device__ __forceinline__ float ftanh(float x) {
  float e = __builtin_amdgcn_exp2f(x * 2.885390081777926f);
  return 1.0f - 2.0f * __builtin_amdgcn_rcpf(1.0f + e);
}
__device__ __forceinline__ h2 pack2(float lo, float hi) {
  return __builtin_amdgcn_cvt_pkrtz(lo, hi);
}
__device__ __forceinline__ float fdot2(h2 a, h2 b, float c) {
  return __builtin_amdgcn_fdot2(a, b, c, false);
}
__device__ __forceinline__ h2 asH2(int v) { return __builtin_bit_cast(h2, v); }

// build (v[2k], v[2k+1]) pairs on even lanes via DPP quad_perm [1,1,3,3]; no DS ops.
__device__ __forceinline__ int pack_pair_dpp(float v) {
  int n_i = __builtin_amdgcn_update_dpp(0, __float_as_int(v), 0xF5, 0xF, 0xF, true);
  return __builtin_bit_cast(int, pack2(v, __int_as_float(n_i)));
}

// ---------------- fully fused LSTM, gate-split recurrence ----------------
// 8 waves per batch element (1 block/CU, 2 waves/SIMD):
//   waves 0-3: gate g = wv  — 18 fdot2 each (wave0 lanes 36/37: y-dot via W_out)
//   waves 4-7: xg producer for gate g = wv-4 (W_ih rows in regs, fp32 out)
// Per step: [gate-dot + act -> gact LDS | producer slice] -> barrier ->
//           [read gact b128, c/h update, pack h, 18 readlanes, xg prefetch].
__global__ __launch_bounds__(512, 1) void lstm_fused(
    const float* __restrict__ x,      // [T][B][64]
    const float* __restrict__ W_ih,   // [144][64]
    const float* __restrict__ W_hh,   // [144][36]
    const float* __restrict__ b_ih,   // [144]
    const float* __restrict__ b_hh,   // [144]
    const float* __restrict__ W_out,  // [2][36]
    const float* __restrict__ b_out,  // [2]
    float* __restrict__ y)            // [T][B][2] fp32
{
  __shared__ float xgb[2][TS][G_];               // 36.9 KiB, fp32 xg tiles
  __shared__ __align__(16) float gact[2][40][4]; // activated gates, dbuf

  const int b   = blockIdx.x;
  const int tid = threadIdx.x;
  const int wv  = tid >> 6;
  const int j   = tid & 63;
  const bool isGate = (wv < 4);
  const int g   = wv & 3;
  const int jr  = (j < H_) ? j : 0;

  h2 wA[18];        // gate wave: W_hh rows of gate g (pairs); wave0 lanes 36/37: W_out
  h2 wp[32];        // producer: W_ih row (gate g, unit j) pairs
  float yb = 0.f, pb = 0.f;
  float hj = 0.f, cj = 0.f;

  if (isGate) {
#pragma unroll
    for (int t = 0; t < 18; ++t) wA[t] = pack2(0.f, 0.f);
    if (j < H_) {
      const float* wr = W_hh + ((size_t)g * H_ + j) * H_;
#pragma unroll
      for (int t = 0; t < 18; ++t) wA[t] = pack2(wr[2 * t], wr[2 * t + 1]);
    } else if (wv == 0 && j < H_ + O_) {
      const float* wr = W_out + (size_t)(j - H_) * H_;
#pragma unroll
      for (int t = 0; t < 18; ++t) wA[t] = pack2(wr[2 * t], wr[2 * t + 1]);
      yb = b_out[j - H_];
    }
  } else {
#pragma unroll
    for (int k = 0; k < 32; ++k) wp[k] = pack2(0.f, 0.f);
    if (j < H_) {
      const int row = g * H_ + j;
      const float* wr = W_ih + (size_t)row * I_;
#pragma unroll
      for (int k = 0; k < 32; ++k) wp[k] = pack2(wr[2 * k], wr[2 * k + 1]);
      pb = b_ih[row] + b_hh[row];
    }
  }

  const float* xlane = x + (size_t)b * I_ + j;   // + t*B*I per timestep
  float xq[8], xqn[8];

  if (!isGate) {
    // prologue: produce tile 0 (timesteps 0..31)
#pragma unroll 1
    for (int ss = 0; ss < TS; ++ss) {
      float xv = xlane[(size_t)ss * (B_ * I_)];
      int xp = pack_pair_dpp(xv);
      float a0 = pb, a1 = 0.f;
#pragma unroll
      for (int p = 0; p < 32; p += 2) {
        h2 pe = asH2(__builtin_amdgcn_readlane(xp, 2 * p));
        h2 po = asH2(__builtin_amdgcn_readlane(xp, 2 * p + 2));
        a0 = fdot2(wp[p], pe, a0);
        a1 = fdot2(wp[p + 1], po, a1);
      }
      if (j < H_) xgb[0][ss][g * H_ + j] = a0 + a1;
    }
    // preload x for main-loop steps 0..7 (timesteps 32..39)
#pragma unroll
    for (int k = 0; k < 8; ++k) xq[k] = xlane[(size_t)(TS + k) * (B_ * I_)];
  }
  __syncthreads();

  int hb[18];
#pragma unroll
  for (int t = 0; t < 18; ++t) hb[t] = 0;
  float xr = 0.f;
  if (isGate) xr = xgb[0][0][g * H_ + jr];

#pragma unroll 1
  for (int s8 = 0; s8 < T_ / 8; ++s8) {
    const int sb = (s8 & 3) << 3;     // slice base within tile
    const int tb = (s8 >> 2) & 1;     // current tile buffer
#pragma unroll
    for (int k = 0; k < 8; ++k) {
      const int s  = (s8 << 3) + k;
      const int sl = sb + k;

      // ---------- phase 1: gate dot + act | producer slice ----------
      if (isGate) {
        float a0 = (j < H_) ? xr : yb;
        float a1 = 0.f;
#pragma unroll
        for (int t = 0; t < 18; t += 2) {
          a0 = fdot2(wA[t],     asH2(hb[t]),     a0);
          a1 = fdot2(wA[t + 1], asH2(hb[t + 1]), a1);
        }
        float av = a0 + a1;
        float actv = (wv == 2) ? ftanh(av) : fsigmoid(av);
        if (j < H_) {
          gact[k & 1][j][g] = actv;
        } else if (wv == 0 && j < H_ + O_ && s > 0) {
          y[((size_t)(s - 1) * B_ + b) * O_ + (j - H_)] = av;  // y[t] = W_out h(t)
        }
      } else {
        if (k == 0) {
          // issue next-chunk x loads (timesteps s+40..s+47, clamped)
#pragma unroll
          for (int q = 0; q < 8; ++q) {
            int t = s + TS + 8 + q; if (t > T_ - 1) t = T_ - 1;
            xqn[q] = xlane[(size_t)t * (B_ * I_)];
          }
        }
        if (s < T_ - TS) {
          int xp = pack_pair_dpp(xq[k]);
          float a0 = pb, a1 = 0.f;
#pragma unroll
          for (int p = 0; p < 32; p += 2) {
            h2 pe = asH2(__builtin_amdgcn_readlane(xp, 2 * p));
            h2 po = asH2(__builtin_amdgcn_readlane(xp, 2 * p + 2));
            a0 = fdot2(wp[p], pe, a0);
            a1 = fdot2(wp[p + 1], po, a1);
          }
          if (j < H_) xgb[tb ^ 1][sl][g * H_ + j] = a0 + a1;  // timestep s+TS
        }
      }
      __syncthreads();

      // ---------- phase 2: update c,h; broadcast h; prefetch xg ----------
      if (isGate) {
        // prefetch next step's xg early (latency hidden under update)
        const int sl1 = (sl + 1) & 31;
        const int nb  = (sl == 31) ? (tb ^ 1) : tb;
        float xrn = xgb[nb][sl1][g * H_ + jr];

        float4 ga = *(const float4*)&gact[k & 1][jr][0];  // (i,f,g,o)
        if (j < H_) {
          cj = ga.y * cj + ga.x * ga.z;
          hj = ga.w * ftanh(cj);
        }
        int hpi = pack_pair_dpp(hj);
#pragma unroll
        for (int t = 0; t < 18; ++t) hb[t] = __builtin_amdgcn_readlane(hpi, 2 * t);
        xr = xrn;
      } else {
        if (k == 7) {
#pragma unroll
          for (int q = 0; q < 8; ++q) xq[q] = xqn[q];
        }
      }
    }
  }

  // ---- epilogue: y[T-1] from final h ----
  if (wv == 0 && (j == H_ || j == H_ + 1)) {
    float a = yb;
#pragma unroll
    for (int t = 0; t < 18; ++t) a = fdot2(wA[t], asH2(hb[t]), a);
    y[((size_t)(T_ - 1) * B_ + b) * O_ + (j - H_)] = a;
  }
}

extern "C" void kernel_launch(void* const* d_in, const int* in_sizes, int n_in,
                              void* d_out, int out_size, void* d_ws, size_t ws_size,
                              hipStream_t stream) {
  const float* x     = (const float*)d_in[0];
  const float* W_ih  = (const float*)d_in[1];
  const float* W_hh  = (const float*)d_in[2];
  const float* b_ih  = (const float*)d_in[3];
  const float* b_hh  = (const float*)d_in[4];
  const float* W_out = (const float*)d_in[5];
  const float* b_out = (const float*)d_in[6];
  float* y           = (float*)d_out;

  lstm_fused<<<dim3(B_), dim3(512), 0, stream>>>(
      x, W_ih, W_hh, b_ih, b_hh, W_out, b_out, y);
}

// Round 15
// 1274.289 us; speedup vs baseline: 1.3551x; 1.3551x over previous
//
#include <hip/hip_runtime.h>
#include <hip/hip_fp16.h>

#define B_ 256
#define T_ 4096
#define I_ 64
#define H_ 36
#define G_ 144   // 4*H
#define O_ 2
#define TS 64            // timesteps per LDS tile
#define NTILES (T_ / TS) // 64
#define UNROLL 8

typedef __fp16 h2 __attribute__((ext_vector_type(2)));

__device__ __forceinline__ float fsigmoid(float x) {
  float e = __builtin_amdgcn_exp2f(x * -1.442695040888963f);
  return __builtin_amdgcn_rcpf(1.0f + e);
}
__device__ __forceinline__ float ftanh(float x) {
  float e = __builtin_amdgcn_exp2f(x * 2.885390081777926f);
  return 1.0f - 2.0f * __builtin_amdgcn_rcpf(1.0f + e);
}
__device__ __forceinline__ h2 pack2(float lo, float hi) {
  return __builtin_amdgcn_cvt_pkrtz(lo, hi);
}
__device__ __forceinline__ float fdot2(h2 a, h2 b, float c) {
  return __builtin_amdgcn_fdot2(a, b, c, false);
}
__device__ __forceinline__ h2 asH2(int v) { return __builtin_bit_cast(h2, v); }

// build (v[2k], v[2k+1]) pairs on even lanes via DPP quad_perm [1,1,3,3]; no DS ops.
__device__ __forceinline__ int pack_pair_dpp(float v) {
  int n_i = __builtin_amdgcn_update_dpp(0, __float_as_int(v), 0xF5, 0xF, 0xF, true);
  return __builtin_bit_cast(int, pack2(v, __int_as_float(n_i)));
}

// ---------------- fully fused LSTM (R13 structure, polished) ----------------
// wave0   = recurrence (in-wave: pack h via DPP, 18 readlane, 72 fdot2, acts)
// wave1/2 = xg producers: W_ih rows in registers (fp16 pairs), x via coalesced
//           lane loads + readlane broadcast, fp32 ds_write_b32 out.
// xg LDS layout per step: [ {i,f} pairs at 2j | 72 + {g,o} pairs at 2j ]
//   -> consumer reads 2x ds_read_b64 per step (was 4x b32).
__global__ __launch_bounds__(192, 1) void lstm_fused(
    const float* __restrict__ x,      // [T][B][64]
    const float* __restrict__ W_ih,   // [144][64]
    const float* __restrict__ W_hh,   // [144][36]
    const float* __restrict__ b_ih,   // [144]
    const float* __restrict__ b_hh,   // [144]
    const float* __restrict__ W_out,  // [2][36]
    const float* __restrict__ b_out,  // [2]
    float* __restrict__ y)            // [T][B][2] fp32
{
  __shared__ float buf[2][TS * G_];   // xg tiles fp32, paired layout: 73.7 KiB
  __shared__ float ybuf[2][TS][O_];   // staged y pairs

  const int b = blockIdx.x;
  const int tid = threadIdx.x;
  const int wv = tid >> 6;            // 0 = consumer, 1/2 = producers
  const int j = tid & 63;

  // ================= consumer state (wave 0) =================
  h2 wA[36], wB[36];                  // wA[0..17]=i pairs, wA[18..35]=f; wB: g,o
  float hj = 0.0f, cj = 0.0f, yb = 0.0f;
  int jj = 0;

  // ================= producer state (waves 1,2) =================
  h2 wp0[32], wp1[32];                // fp16 pairs of W_ih rows rowA / rowB
  float bias0 = 0.f, bias1 = 0.f;
  int offA = 0, offB = 0;             // paired-layout dword offsets within a step
  bool hasB = false;

  // paired-layout offset for gate-major row r: g=r/36, u=r%36
  auto rowoff = [](int r) {
    int g = r / 36, u = r - g * 36;
    return ((g >> 1) ? 72 : 0) + u * 2 + (g & 1);
  };

  if (wv == 0) {
    if (j < H_) {
#pragma unroll
      for (int t = 0; t < 18; t++) {
        wA[t]      = pack2(W_hh[j * H_ + 2 * t],            W_hh[j * H_ + 2 * t + 1]);
        wA[18 + t] = pack2(W_hh[(j + H_) * H_ + 2 * t],     W_hh[(j + H_) * H_ + 2 * t + 1]);
        wB[t]      = pack2(W_hh[(j + 2 * H_) * H_ + 2 * t], W_hh[(j + 2 * H_) * H_ + 2 * t + 1]);
        wB[18 + t] = pack2(W_hh[(j + 3 * H_) * H_ + 2 * t], W_hh[(j + 3 * H_) * H_ + 2 * t + 1]);
      }
    } else if (j < H_ + O_) {
      const int o = j - H_;
#pragma unroll
      for (int t = 0; t < 18; t++) {
        wA[t] = pack2(W_out[o * H_ + 2 * t], W_out[o * H_ + 2 * t + 1]);
        wA[18 + t] = pack2(0.f, 0.f);
        wB[t] = pack2(0.f, 0.f); wB[18 + t] = pack2(0.f, 0.f);
      }
      yb = b_out[o];
    } else {
#pragma unroll
      for (int k = 0; k < H_; k++) { wA[k] = pack2(0.f, 0.f); wB[k] = pack2(0.f, 0.f); }
    }
    jj = (j < H_) ? j : 0;
    __builtin_amdgcn_s_setprio(1);
  } else {
    // rows: wave1 -> 0..71, wave2 -> 72..143 (64 via rowA, 8 via rowB on lanes 0..7)
    const int base = (wv - 1) * 72;
    const int rowA = base + j;
    hasB = (j < 8);
    const int rowB = base + 64 + (j & 7);
    offA = rowoff(rowA);
    offB = rowoff(rowB);
#pragma unroll
    for (int k = 0; k < 32; k++) {
      wp0[k] = pack2(W_ih[rowA * I_ + 2 * k], W_ih[rowA * I_ + 2 * k + 1]);
      wp1[k] = hasB ? pack2(W_ih[rowB * I_ + 2 * k], W_ih[rowB * I_ + 2 * k + 1])
                    : pack2(0.f, 0.f);
    }
    bias0 = b_ih[rowA] + b_hh[rowA];
    bias1 = hasB ? (b_ih[rowB] + b_hh[rowB]) : 0.f;
  }

  // ---- producer: compute one tile's xg into dst ----
  auto produce = [&](int tt, float* dst) {
    const float* xcol = x + ((size_t)(tt * TS) * B_ + b) * I_ + j;
#pragma unroll 1
    for (int c4 = 0; c4 < TS / 4; ++c4) {
      float xa[4];
#pragma unroll
      for (int u = 0; u < 4; ++u)
        xa[u] = xcol[(size_t)(c4 * 4 + u) * (B_ * I_)];
#pragma unroll
      for (int u = 0; u < 4; ++u) {
        const int s = c4 * 4 + u;
        int xp = pack_pair_dpp(xa[u]);
        float a0e = bias0, a0o = 0.f, a1e = bias1, a1o = 0.f;
#pragma unroll
        for (int k = 0; k < 32; k += 2) {
          h2 pe = asH2(__builtin_amdgcn_readlane(xp, 2 * k));
          h2 po = asH2(__builtin_amdgcn_readlane(xp, 2 * k + 2));
          a0e = fdot2(wp0[k], pe, a0e);
          a0o = fdot2(wp0[k + 1], po, a0o);
          a1e = fdot2(wp1[k], pe, a1e);
          a1o = fdot2(wp1[k + 1], po, a1o);
        }
        dst[s * G_ + offA] = a0e + a0o;
        if (hasB) dst[s * G_ + offB] = a1e + a1o;
      }
    }
  };

  // ---- prologue: produce tile 0 ----
  if (wv >= 1) produce(0, &buf[0][0]);
  __syncthreads();

  for (int tile = 0; tile < NTILES; ++tile) {
    if (wv >= 1) {
      // wave1: flush previous tile's staged y (off the recurrence path)
      if (wv == 1 && tile >= 1) {
        const int tp = tile - 1;
#pragma unroll
        for (int q = 0; q < 2; ++q) {
          const int v = q * 64 + j;
          const int s = v >> 1, o = v & 1;
          const int gt = tp * TS + s - 1;
          float vv = ybuf[tp & 1][s][o];
          if (gt >= 0) y[((size_t)gt * B_ + b) * O_ + o] = vv;
        }
      }
      if (tile + 1 < NTILES) produce(tile + 1, &buf[(tile + 1) & 1][0]);
    } else {
      const float* bp = &buf[tile & 1][0];
#pragma unroll 1
      for (int ch = 0; ch < TS / UNROLL; ++ch) {
        // batch-load the chunk's gate pre-activations: 2 x b64 per step
        float2 xif[UNROLL], xgo[UNROLL];
#pragma unroll
        for (int k = 0; k < UNROLL; ++k) {
          const int s = ch * UNROLL + k;
          xif[k] = *(const float2*)&bp[s * G_ + 2 * jj];
          xgo[k] = *(const float2*)&bp[s * G_ + 72 + 2 * jj];
        }

#pragma unroll
        for (int k = 0; k < UNROLL; ++k) {
          const int s = ch * UNROLL + k;

          int hpi = pack_pair_dpp(hj);
          int hb[18];
#pragma unroll
          for (int t = 0; t < 18; ++t) hb[t] = __builtin_amdgcn_readlane(hpi, 2 * t);

          float a_i0, a_f0, a_g0, a_o0;
          if (j < H_) {
            a_i0 = xif[k].x; a_f0 = xif[k].y;
            a_g0 = xgo[k].x; a_o0 = xgo[k].y;
          } else {
            a_i0 = yb; a_f0 = 0.f; a_g0 = 0.f; a_o0 = 0.f;
          }
          float a_i1 = 0.f, a_f1 = 0.f, a_g1 = 0.f, a_o1 = 0.f;
#pragma unroll
          for (int t = 0; t < 18; t += 2) {
            h2 hh0 = asH2(hb[t]);
            h2 hh1 = asH2(hb[t + 1]);
            a_i0 = fdot2(wA[t], hh0, a_i0);       a_i1 = fdot2(wA[t + 1], hh1, a_i1);
            a_f0 = fdot2(wA[18 + t], hh0, a_f0);  a_f1 = fdot2(wA[18 + t + 1], hh1, a_f1);
            a_g0 = fdot2(wB[t], hh0, a_g0);       a_g1 = fdot2(wB[t + 1], hh1, a_g1);
            a_o0 = fdot2(wB[18 + t], hh0, a_o0);  a_o1 = fdot2(wB[18 + t + 1], hh1, a_o1);
          }
          float a_i = a_i0 + a_i1;

          if (j < H_) {
            float ig = fsigmoid(a_i);
            float fg = fsigmoid(a_f0 + a_f1);
            float gg = ftanh(a_g0 + a_g1);
            float og = fsigmoid(a_o0 + a_o1);
            cj = fg * cj + ig * gg;
            hj = og * ftanh(cj);
          } else if (j < H_ + O_) {
            ybuf[tile & 1][s][j - H_] = a_i;
          }
        }
      }
    }
    __syncthreads();
  }

  // ---- epilogue ----
  if (wv == 1) {
    const int tp = NTILES - 1;
#pragma unroll
    for (int q = 0; q < 2; ++q) {
      const int v = q * 64 + j;
      const int s = v >> 1, o = v & 1;
      const int gt = tp * TS + s - 1;
      float vv = ybuf[tp & 1][s][o];
      if (gt >= 0) y[((size_t)gt * B_ + b) * O_ + o] = vv;
    }
  } else if (wv == 0) {
    __builtin_amdgcn_s_setprio(0);
    // last y (t = T-1) directly from final h
    int hpi = pack_pair_dpp(hj);
    float a = yb;
#pragma unroll
    for (int t = 0; t < 18; ++t) {
      a = fdot2(wA[t], asH2(__builtin_amdgcn_readlane(hpi, 2 * t)), a);
    }
    if (j == H_ || j == H_ + 1) {
      y[((size_t)(T_ - 1) * B_ + b) * O_ + (j - H_)] = a;
    }
  }
}

extern "C" void kernel_launch(void* const* d_in, const int* in_sizes, int n_in,
                              void* d_out, int out_size, void* d_ws, size_t ws_size,
                              hipStream_t stream) {
  const float* x     = (const float*)d_in[0];
  const float* W_ih  = (const float*)d_in[1];
  const float* W_hh  = (const float*)d_in[2];
  const float* b_ih  = (const float*)d_in[3];
  const float* b_hh  = (const float*)d_in[4];
  const float* W_out = (const float*)d_in[5];
  const float* b_out = (const float*)d_in[6];
  float* y           = (float*)d_out;

  lstm_fused<<<dim3(B_), dim3(192), 0, stream>>>(
      x, W_ih, W_hh, b_ih, b_hh, W_out, b_out, y);
}